// Round 10
// baseline (308.776 us; speedup 1.0000x reference)
//
#include <hip/hip_runtime.h>

// Problem constants (reference: B,S,M,D,NQ = 128,100,50,128,10000)
#define BB 128
#define SS 100
#define MM 50
#define DD 128
#define KROW 66                          // key row stride (u32 words), no overlap (r7 bug fixed in r8)
#define W2ROW(r) ((r) * 68 + (((r) >> 5) << 3))  // w2 staging: swizzled rows -> q-group reads 2-way (free)
#define WADDR(w) ((w) + 8 * ((w) >> 4))          // stage-vector (bf16-packed) word address, w in [0,64)

// ---- bf16 helpers (pure integer bit ops) ----
__device__ __forceinline__ float bf2f(unsigned short u) {
    union { unsigned int i; float f; } c; c.i = ((unsigned int)u) << 16; return c.f;
}
__device__ __forceinline__ float bfu_lo(unsigned int u) {
    union { unsigned int i; float f; } c; c.i = u << 16; return c.f;
}
__device__ __forceinline__ float bfu_hi(unsigned int u) {
    union { unsigned int i; float f; } c; c.i = u & 0xffff0000u; return c.f;
}
__device__ __forceinline__ unsigned short f2bf_bits(float f) {   // RNE
    union { float f; unsigned int u; } c; c.f = f;
    unsigned int r = (c.u + 0x7FFFu + ((c.u >> 16) & 1u)) >> 16;
    return (unsigned short)r;
}
__device__ __forceinline__ unsigned int packbf(float lo, float hi) {
    return (unsigned int)f2bf_bits(lo) | ((unsigned int)f2bf_bits(hi) << 16);
}
__device__ __forceinline__ float fast_sigmoid(float x) { return 1.0f / (1.0f + __expf(-x)); }
__device__ __forceinline__ float fast_tanh(float x) {
    float ax = fabsf(x);
    float z = __expf(-2.0f * ax);
    float r = (1.0f - z) / (1.0f + z);
    return copysignf(r, x);
}

template <bool BF16>
__device__ __forceinline__ float ldw(const void* p, size_t idx) {
    if (BF16) return bf2f(((const unsigned short*)p)[idx]);
    return ((const float*)p)[idx];
}

struct __align__(16) SmemT {
    union {
        struct {                          // staging phase
            unsigned int key_w[MM * KROW];    // 13200 B
            unsigned int qe8[8][68];          // 2176 B
        } pre;                            // 15376 B
        struct {                          // scan phase (first 1280 B of key_w region; qe8 untouched)
            unsigned int xread_w[96];         // bf16-packed, WADDR layout
            unsigned int xh_w[96];
            float h1f[DD];
        } run;
    } u;
    union {
        unsigned int w2s[8724];           // 34896 B: swizzled w2 rows (build phase)
        struct {                          // table phase (overwrites w2s after build)
            unsigned int wrow_p[SS][32];      // 12800 B bf16 attention rows (m>=50 zero)
            unsigned short qp_all[SS][DD];    // 25600 B bf16 qe-projections
        } tab;
    } v2;                                 // 38400 B
    int qrow[SS];                         // 400 B
    float qlast[DD];                      // 512 B
};                                        // 54688 B < 64 KB

// 512 threads: wave wv=t>>6, lane l=t&63; d = 16*wv + (l&15); q = l>>4 (k-quarter).
// v[m][d] for m = 16q+j (m>=50 inert: wrow==0).
// Registers: rw1a (w1 read-half col), rw2e = (w2@er) col, rw2a = (w2@ad) col.
// __launch_bounds__(512,2): 2 waves/EU min -> 256-VGPR cap; the ~200-float live set
// (incl. the COMPUTED rw2e/rw2a, which cannot be rematerialized from global) stays
// in registers. r9's 128-VGPR allocation spilled them to scratch every step.
template <bool BF16>
__device__ void dkvmn_impl(
    const int* __restrict__ qseq,
    const void* emb, const void* key,
    const void* vu_w1, const void* vu_b1, const void* vu_w2, const void* vu_b2,
    const void* er_w, const void* er_b, const void* ad_w, const void* ad_b,
    const void* out_w1, const void* out_b1, const void* out_w2, const void* out_b2,
    void* outp, SmemT& sm)
{
    const int t = threadIdx.x;
    const int b = blockIdx.x;
    const int l = t & 63;
    const int wv = t >> 6;
    const int d = (wv << 4) + (l & 15);
    const int q = l >> 4;

    // ---- stage key (stride 66), w2 (swizzled rows), qrow ----
    if (BF16) {
        const unsigned int* kg = (const unsigned int*)key;
        for (int g = t; g < MM * 64; g += 512)
            sm.u.pre.key_w[(g >> 6) * KROW + (g & 63)] = kg[g];
        const unsigned int* wg = (const unsigned int*)vu_w2;
        for (int g = t; g < 128 * 64; g += 512)
            sm.v2.w2s[W2ROW(g >> 6) + (g & 63)] = wg[g];
    } else {
        const float* kf = (const float*)key;
        for (int g = t; g < MM * 64; g += 512) {
            int row = g >> 6, c2 = g & 63;
            sm.u.pre.key_w[row * KROW + c2] = packbf(kf[row * 128 + 2 * c2], kf[row * 128 + 2 * c2 + 1]);
        }
        const float* wf = (const float*)vu_w2;
        for (int g = t; g < 128 * 64; g += 512) {
            int row = g >> 6, c2 = g & 63;
            sm.v2.w2s[W2ROW(row) + c2] = packbf(wf[row * 128 + 2 * c2], wf[row * 128 + 2 * c2 + 1]);
        }
    }
    for (int g = t; g < SS; g += 512) sm.qrow[g] = qseq[b * SS + g];
    __syncthreads();

    // ---- build fused columns: rw2e[k] = (w2@er)[32q+k][d], rw2a likewise; fused biases ----
    float rw2e[32], rw2a[32];
#pragma unroll
    for (int k = 0; k < 32; ++k) { rw2e[k] = 0.f; rw2a[k] = 0.f; }
    float ebias = 0.f, abias = 0.f;
#pragma unroll 1
    for (int jc = 0; jc < 4; ++jc) {
        float ec[32], ac[32];
#pragma unroll
        for (int i = 0; i < 32; ++i) {
            int j = 32 * jc + i;
            ec[i] = ldw<BF16>(er_w, (size_t)j * DD + d);
            ac[i] = ldw<BF16>(ad_w, (size_t)j * DD + d);
            float b2j = ldw<BF16>(vu_b2, j);
            ebias = fmaf(b2j, ec[i], ebias);
            abias = fmaf(b2j, ac[i], abias);
        }
#pragma unroll
        for (int k = 0; k < 32; ++k) {
            const uint4* wp = (const uint4*)&sm.v2.w2s[W2ROW(32 * q + k) + 16 * jc];
            uint4 A = wp[0], B = wp[1], C = wp[2], Dv = wp[3];
            unsigned int W[16] = { A.x, A.y, A.z, A.w, B.x, B.y, B.z, B.w,
                                   C.x, C.y, C.z, C.w, Dv.x, Dv.y, Dv.z, Dv.w };
            float se = rw2e[k], sa = rw2a[k];
#pragma unroll
            for (int wd = 0; wd < 16; ++wd) {
                float wlo = bfu_lo(W[wd]), whi = bfu_hi(W[wd]);
                se = fmaf(wlo, ec[2 * wd], se);     se = fmaf(whi, ec[2 * wd + 1], se);
                sa = fmaf(wlo, ac[2 * wd], sa);     sa = fmaf(whi, ac[2 * wd + 1], sa);
            }
            rw2e[k] = se; rw2a[k] = sa;
        }
    }
    ebias += ldw<BF16>(er_b, d);
    abias += ldw<BF16>(ad_b, d);
    __syncthreads();   // w2s consumed -> v2 region becomes tab

    // ---- w1 columns into registers ----
    float rw1a[32], rw1b[32];
#pragma unroll
    for (int i = 0; i < 32; ++i) {
        int k = 32 * q + i;
        rw1a[i] = ldw<BF16>(vu_w1, (size_t)k * DD + d);
        rw1b[i] = ldw<BF16>(vu_w1, (size_t)(DD + k) * DD + d);
    }
    const float b1r = ldw<BF16>(vu_b1, d);

    // ================= PRECOMPUTE: softmax rows + qe-projections =================
    for (int ii = 0; ii < 13; ++ii) {
        const int nrows = (ii == 12) ? 4 : 8;
        {
            int r = t >> 6, w = t & 63;
            if (r < nrows) {
                int row = sm.qrow[8 * ii + r];
                if (BF16) {
                    sm.u.pre.qe8[r][w] = ((const unsigned int*)emb)[((size_t)row << 6) + w];
                } else {
                    const float* ef = (const float*)emb + (((size_t)row) << 7) + 2 * w;
                    sm.u.pre.qe8[r][w] = packbf(ef[0], ef[1]);
                }
            }
        }
        __syncthreads();

        // logits + softmax: wave wv handles s = 8*ii + wv (lane m = l)
        if (wv < nrows) {
            int m = l;
            int mc = (m < MM) ? m : (MM - 1);
            float a0 = 0.f, a1 = 0.f, a2 = 0.f, a3 = 0.f;
#pragma unroll
            for (int j = 0; j < 32; ++j) {
                uint2 kw = *(const uint2*)&sm.u.pre.key_w[mc * KROW + 2 * j];
                uint2 qw = *(const uint2*)&sm.u.pre.qe8[wv][2 * j];
                a0 = fmaf(bfu_lo(kw.x), bfu_lo(qw.x), a0);
                a1 = fmaf(bfu_hi(kw.x), bfu_hi(qw.x), a1);
                a2 = fmaf(bfu_lo(kw.y), bfu_lo(qw.y), a2);
                a3 = fmaf(bfu_hi(kw.y), bfu_hi(qw.y), a3);
            }
            float lg = (a0 + a1) + (a2 + a3);
            if (m >= MM) lg = -1e30f;
            float mx = lg;
#pragma unroll
            for (int o = 32; o > 0; o >>= 1) mx = fmaxf(mx, __shfl_xor(mx, o));
            float p = (m < MM) ? __expf(lg - mx) : 0.f;
            float sum = p;
#pragma unroll
            for (int o = 32; o > 0; o >>= 1) sum += __shfl_xor(sum, o);
            p = p / sum;
            float pn = __shfl_xor(p, 1);
            if ((m & 1) == 0)
                sm.v2.tab.wrow_p[8 * ii + wv][m >> 1] = packbf(p, pn);
        }

        // qe-projection: thread (d,q), k in [32q, 32q+32)
        for (int sr = 0; sr < nrows; ++sr) {
            float p0 = 0.f, p1 = 0.f;
#pragma unroll
            for (int i = 0; i < 16; ++i) {
                unsigned int uw = sm.u.pre.qe8[sr][16 * q + i];
                p0 = fmaf(rw1b[2 * i],     bfu_lo(uw), p0);
                p1 = fmaf(rw1b[2 * i + 1], bfu_hi(uw), p1);
            }
            float qpv = p0 + p1;
            qpv += __shfl_xor(qpv, 16);
            qpv += __shfl_xor(qpv, 32);
            if (q == 0) sm.v2.tab.qp_all[8 * ii + sr][d] = f2bf_bits(qpv);
        }
        __syncthreads();
    }

    // save last qe (s=99 lives in qe8[3]); init scan state
    if (t < 64) {
        unsigned int uw = sm.u.pre.qe8[3][t];
        sm.qlast[2 * t]     = bfu_lo(uw);
        sm.qlast[2 * t + 1] = bfu_hi(uw);
    }
    float v[16];
#pragma unroll
    for (int j = 0; j < 16; ++j) v[j] = 0.f;
    float wrowr[16];
    {
        const uint4* wp = (const uint4*)&sm.v2.tab.wrow_p[0][8 * q];
        uint4 w0 = wp[0], w1 = wp[1];
        unsigned int ww[8] = { w0.x, w0.y, w0.z, w0.w, w1.x, w1.y, w1.z, w1.w };
#pragma unroll
        for (int i = 0; i < 8; ++i) { wrowr[2 * i] = bfu_lo(ww[i]); wrowr[2 * i + 1] = bfu_hi(ww[i]); }
    }
    if (t < 96) sm.u.run.xread_w[t] = 0;   // read0 = 0 (v0 = 0); bf16 zeros
    __syncthreads();

    // ================= SCAN: 2 barriers per step =================
    for (int s = 0; s < SS; ++s) {
        // ---- E: h = tanh(read @ w1a + qp + b1) ----
        {
            float qpv = bf2f(sm.v2.tab.qp_all[s][d]);
            const uint4* xp = (const uint4*)&sm.u.run.xread_w[24 * q];
            uint4 X0 = xp[0], X1 = xp[1], X2 = xp[2], X3 = xp[3];
            unsigned int W[16] = { X0.x, X0.y, X0.z, X0.w, X1.x, X1.y, X1.z, X1.w,
                                   X2.x, X2.y, X2.z, X2.w, X3.x, X3.y, X3.z, X3.w };
            float a0 = 0.f, a1 = 0.f, a2 = 0.f, a3 = 0.f;
#pragma unroll
            for (int wd = 0; wd < 8; ++wd) {
                a0 = fmaf(rw1a[2 * wd],      bfu_lo(W[wd]), a0);
                a1 = fmaf(rw1a[2 * wd + 1],  bfu_hi(W[wd]), a1);
                a2 = fmaf(rw1a[2 * wd + 16], bfu_lo(W[wd + 8]), a2);
                a3 = fmaf(rw1a[2 * wd + 17], bfu_hi(W[wd + 8]), a3);
            }
            float acc = (a0 + a1) + (a2 + a3);
            acc += __shfl_xor(acc, 16);
            acc += __shfl_xor(acc, 32);
            float hh = fast_tanh(acc + qpv + b1r);
            float hp = __shfl_xor(hh, 1);
            if (q == 0 && !(d & 1)) sm.u.run.xh_w[WADDR(d >> 1)] = packbf(hh, hp);
        }
        __syncthreads();

        // ---- G: e = sigmoid(h@W2E + ebias), a = tanh(h@W2A + abias); v-update; next read ----
        {
            const uint4* xp = (const uint4*)&sm.u.run.xh_w[24 * q];
            uint4 X0 = xp[0], X1 = xp[1], X2 = xp[2], X3 = xp[3];
            unsigned int W[16] = { X0.x, X0.y, X0.z, X0.w, X1.x, X1.y, X1.z, X1.w,
                                   X2.x, X2.y, X2.z, X2.w, X3.x, X3.y, X3.z, X3.w };
            float e0 = 0.f, e1 = 0.f, e2 = 0.f, e3 = 0.f;
            float f0 = 0.f, f1 = 0.f, f2 = 0.f, f3 = 0.f;
#pragma unroll
            for (int wd = 0; wd < 8; ++wd) {
                float wlo = bfu_lo(W[wd]), whi = bfu_hi(W[wd]);
                float vlo = bfu_lo(W[wd + 8]), vhi = bfu_hi(W[wd + 8]);
                e0 = fmaf(rw2e[2 * wd],      wlo, e0);
                e1 = fmaf(rw2e[2 * wd + 1],  whi, e1);
                e2 = fmaf(rw2e[2 * wd + 16], vlo, e2);
                e3 = fmaf(rw2e[2 * wd + 17], vhi, e3);
                f0 = fmaf(rw2a[2 * wd],      wlo, f0);
                f1 = fmaf(rw2a[2 * wd + 1],  whi, f1);
                f2 = fmaf(rw2a[2 * wd + 16], vlo, f2);
                f3 = fmaf(rw2a[2 * wd + 17], vhi, f3);
            }
            float ae = (e0 + e1) + (e2 + e3), aa = (f0 + f1) + (f2 + f3);
            ae += __shfl_xor(ae, 16); ae += __shfl_xor(ae, 32);
            aa += __shfl_xor(aa, 16); aa += __shfl_xor(aa, 32);
            float e = fast_sigmoid(ae + ebias);
            float a = fast_tanh(aa + abias);
#pragma unroll
            for (int j = 0; j < 16; ++j)
                v[j] = fmaf(wrowr[j], fmaf(-e, v[j], a), v[j]);
            if (s + 1 < SS) {   // advance to wrow[s+1]; at s=99 keep wrow[99] for the final read
                const uint4* wp = (const uint4*)&sm.v2.tab.wrow_p[s + 1][8 * q];
                uint4 w0 = wp[0], w1 = wp[1];
                unsigned int ww[8] = { w0.x, w0.y, w0.z, w0.w, w1.x, w1.y, w1.z, w1.w };
#pragma unroll
                for (int i = 0; i < 8; ++i) { wrowr[2 * i] = bfu_lo(ww[i]); wrowr[2 * i + 1] = bfu_hi(ww[i]); }
            }
            float r0 = 0.f, r1 = 0.f;
#pragma unroll
            for (int j = 0; j < 16; j += 2) {
                r0 = fmaf(wrowr[j], v[j], r0);
                r1 = fmaf(wrowr[j + 1], v[j + 1], r1);
            }
            float rr = r0 + r1;
            rr += __shfl_xor(rr, 16);
            rr += __shfl_xor(rr, 32);
            float rp = __shfl_xor(rr, 1);
            if (q == 0 && !(d & 1)) sm.u.run.xread_w[WADDR(d >> 1)] = packbf(rr, rp);
        }
        __syncthreads();
    }

    // ---- Epilogue: xread_w holds final read (bf16); qlast holds qe[99] (f32) ----
    float acc = 0.f;
    if (q < 2) {
        const uint4* xr0 = (const uint4*)&sm.u.run.xread_w[48 * q];
        const uint4* xr1 = (const uint4*)&sm.u.run.xread_w[48 * q + 24];
#pragma unroll
        for (int half = 0; half < 2; ++half) {
            const uint4* xp = half ? xr1 : xr0;
#pragma unroll
            for (int wq = 0; wq < 4; ++wq) {
                uint4 X = xp[wq];
                unsigned int Wv[4] = { X.x, X.y, X.z, X.w };
#pragma unroll
                for (int e2 = 0; e2 < 4; ++e2) {
                    int k = 64 * q + 32 * half + 8 * wq + 2 * e2;
                    acc = fmaf(ldw<BF16>(out_w1, (size_t)k * DD + d),       bfu_lo(Wv[e2]), acc);
                    acc = fmaf(ldw<BF16>(out_w1, (size_t)(k + 1) * DD + d), bfu_hi(Wv[e2]), acc);
                }
            }
        }
    } else {
        int half = q - 2;
        const float4* qp4 = (const float4*)&sm.qlast[64 * half];
#pragma unroll
        for (int j = 0; j < 16; ++j) {
            float4 xv = qp4[j];
            int k = DD + 64 * half + 4 * j;
            acc = fmaf(ldw<BF16>(out_w1, (size_t)k * DD + d),       xv.x, acc);
            acc = fmaf(ldw<BF16>(out_w1, (size_t)(k + 1) * DD + d), xv.y, acc);
            acc = fmaf(ldw<BF16>(out_w1, (size_t)(k + 2) * DD + d), xv.z, acc);
            acc = fmaf(ldw<BF16>(out_w1, (size_t)(k + 3) * DD + d), xv.w, acc);
        }
    }
    acc += __shfl_xor(acc, 16);
    acc += __shfl_xor(acc, 32);
    float h1 = fmaxf(acc + ldw<BF16>(out_b1, d), 0.f);
    if (q == 0) sm.u.run.h1f[d] = h1;
    __syncthreads();

    if (t < 64) {
        float xs = fmaf(sm.u.run.h1f[t], ldw<BF16>(out_w2, t),
                        sm.u.run.h1f[64 + t] * ldw<BF16>(out_w2, 64 + t));
#pragma unroll
        for (int o = 32; o > 0; o >>= 1) xs += __shfl_xor(xs, o);
        if (t == 0) {
            float pred = fast_sigmoid(xs + ldw<BF16>(out_b2, 0));
            if (BF16) ((unsigned short*)outp)[b] = f2bf_bits(pred);
            else      ((float*)outp)[b] = pred;
        }
    }
}

__global__ __launch_bounds__(512, 2) void DKVMN_78546361909953_kernel(
    const int* __restrict__ qseq,
    const void* emb, const void* key,
    const void* vu_w1, const void* vu_b1, const void* vu_w2, const void* vu_b2,
    const void* er_w, const void* er_b, const void* ad_w, const void* ad_b,
    const void* out_w1, const void* out_b1, const void* out_w2, const void* out_b2,
    void* outp)
{
    __shared__ SmemT sm;

    // Runtime storage-dtype detection (proven rounds 5-9: BF16 path taken).
    const unsigned int* eu = (const unsigned int*)emb;
    int cnt = 0;
    for (int i = 0; i < 32; ++i) {
        unsigned int e8 = (eu[i] >> 7) & 0xFFu;
        cnt += (e8 >= 100u && e8 <= 127u) ? 1 : 0;
    }
    if (cnt >= 16)
        dkvmn_impl<true>(qseq, emb, key, vu_w1, vu_b1, vu_w2, vu_b2,
                         er_w, er_b, ad_w, ad_b, out_w1, out_b1, out_w2, out_b2, outp, sm);
    else
        dkvmn_impl<false>(qseq, emb, key, vu_w1, vu_b1, vu_w2, vu_b2,
                          er_w, er_b, ad_w, ad_b, out_w1, out_b1, out_w2, out_b2, outp, sm);
}

extern "C" void kernel_launch(void* const* d_in, const int* in_sizes, int n_in,
                              void* d_out, int out_size, void* d_ws, size_t ws_size,
                              hipStream_t stream) {
    const int* qseq = (const int*)d_in[0];
    // d_in[1] = answer_seq: unused by the reference
    DKVMN_78546361909953_kernel<<<BB, 512, 0, stream>>>(
        qseq,
        d_in[2], d_in[3], d_in[4], d_in[5], d_in[6], d_in[7],
        d_in[8], d_in[9], d_in[10], d_in[11],
        d_in[12], d_in[13], d_in[14], d_in[15],
        d_out);
}

// Round 11
// 282.377 us; speedup vs baseline: 1.0935x; 1.0935x over previous
//
#include <hip/hip_runtime.h>

// Problem constants (reference: B,S,M,D,NQ = 128,100,50,128,10000)
#define BB 128
#define SS 100
#define MM 50
#define DD 128
#define KROW 66                        // key row stride (u32 words), no overlap
#define XW(k) ((k) + 8 * ((k) >> 5))   // plain f32 stage buffer: q-slices on disjoint banks
#define DUPW(k) ((k) + 8 * ((k) >> 5)) // duplicated f32 stage buffer word address

typedef float f32x2 __attribute__((ext_vector_type(2)));

#if defined(__has_builtin)
#  if __has_builtin(__builtin_elementwise_fma)
#    define HAVE_PKFMA 1
#  endif
#  if __has_builtin(__builtin_amdgcn_update_dpp)
#    define HAVE_DPP 1
#  endif
#endif

__device__ __forceinline__ f32x2 pkfma(f32x2 a, f32x2 b, f32x2 c) {
#ifdef HAVE_PKFMA
    return __builtin_elementwise_fma(a, b, c);
#else
    f32x2 r; r.x = fmaf(a.x, b.x, c.x); r.y = fmaf(a.y, b.y, c.y); return r;
#endif
}

// quad butterfly add: after xor1+xor2 all 4 lanes of a quad hold the quad sum
__device__ __forceinline__ float qbf_add(float x) {
#ifdef HAVE_DPP
    union { float f; int i; } c, o;
    c.f = x;
    o.i = __builtin_amdgcn_update_dpp(0, c.i, 0xB1, 0xF, 0xF, true);  // quad_perm(1,0,3,2) = xor1
    x += o.f;
    c.f = x;
    o.i = __builtin_amdgcn_update_dpp(0, c.i, 0x4E, 0xF, 0xF, true);  // quad_perm(2,3,0,1) = xor2
    return x + o.f;
#else
    x += __shfl_xor(x, 1);
    x += __shfl_xor(x, 2);
    return x;
#endif
}

// ---- bf16 helpers ----
__device__ __forceinline__ float bf2f(unsigned short u) {
    union { unsigned int i; float f; } c; c.i = ((unsigned int)u) << 16; return c.f;
}
__device__ __forceinline__ float bfu_lo(unsigned int u) {
    union { unsigned int i; float f; } c; c.i = u << 16; return c.f;
}
__device__ __forceinline__ float bfu_hi(unsigned int u) {
    union { unsigned int i; float f; } c; c.i = u & 0xffff0000u; return c.f;
}
__device__ __forceinline__ unsigned short f2bf_bits(float f) {   // RNE
    union { float f; unsigned int u; } c; c.f = f;
    unsigned int r = (c.u + 0x7FFFu + ((c.u >> 16) & 1u)) >> 16;
    return (unsigned short)r;
}
__device__ __forceinline__ unsigned int packbf(float lo, float hi) {
    return (unsigned int)f2bf_bits(lo) | ((unsigned int)f2bf_bits(hi) << 16);
}
__device__ __forceinline__ float fast_sigmoid(float x) { return 1.0f / (1.0f + __expf(-x)); }
__device__ __forceinline__ float fast_tanh(float x) {
    float ax = fabsf(x);
    float z = __expf(-2.0f * ax);
    float r = (1.0f - z) / (1.0f + z);
    return copysignf(r, x);
}

template <bool BF16>
__device__ __forceinline__ float ldw(const void* p, size_t idx) {
    if (BF16) return bf2f(((const unsigned short*)p)[idx]);
    return ((const float*)p)[idx];
}

#define W2ROW(r) ((r) * 68 + (((r) >> 5) << 3))  // w2 staging rows (build phase)

struct __align__(16) SmemT {
    union {
        struct {                          // staging phase
            unsigned int key_w[MM * KROW];    // 13200 B
            unsigned int qe8[8][68];          // 2176 B
        } pre;                            // 15376 B
        struct {                          // scan phase (fits in pre region)
            float xread[152];                 // plain f32, XW layout
            float xhdup[312];                 // duplicated f32, DUPW layout
            float h1f[DD];
        } run;                            // 2368 B
    } u;
    union {
        unsigned int w2s[8724];           // 34896 B (build phase)
        struct {                          // table phase
            unsigned int wrow_p[SS][32];      // 12800 B: word q*8+p = packbf(w[8p+q], w[8p+4+q])
            unsigned short qp_all[SS][DD];    // 25600 B
        } tab;
    } v2;                                 // 38400 B
    int qrow[SS];                         // 400 B
    float qlast[DD];                      // 512 B
};                                        // 54688 B < 64 KB

// 512 threads: wave wv=t>>6, lane l=t&63; q = l&3 (k-quarter), d = wv*16 + (l>>2).
// Quad = 4 lanes of one d -> cross-q reduce is a DPP butterfly.
// v2[p] holds (v[m=8p+q][d], v[m=8p+4+q][d]) as f32x2, p<7 (m>=50 inert: wrow==0).
template <bool BF16>
__device__ void dkvmn_impl(
    const int* __restrict__ qseq,
    const void* emb, const void* key,
    const void* vu_w1, const void* vu_b1, const void* vu_w2, const void* vu_b2,
    const void* er_w, const void* er_b, const void* ad_w, const void* ad_b,
    const void* out_w1, const void* out_b1, const void* out_w2, const void* out_b2,
    void* outp, SmemT& sm)
{
    const int t = threadIdx.x;
    const int b = blockIdx.x;
    const int l = t & 63;
    const int wv = t >> 6;
    const int q = l & 3;
    const int d = (wv << 4) + (l >> 2);

    // ---- stage key (stride 66), w2 (swizzled rows), qrow ----
    if (BF16) {
        const unsigned int* kg = (const unsigned int*)key;
        for (int g = t; g < MM * 64; g += 512)
            sm.u.pre.key_w[(g >> 6) * KROW + (g & 63)] = kg[g];
        const unsigned int* wg = (const unsigned int*)vu_w2;
        for (int g = t; g < 128 * 64; g += 512)
            sm.v2.w2s[W2ROW(g >> 6) + (g & 63)] = wg[g];
    } else {
        const float* kf = (const float*)key;
        for (int g = t; g < MM * 64; g += 512) {
            int row = g >> 6, c2 = g & 63;
            sm.u.pre.key_w[row * KROW + c2] = packbf(kf[row * 128 + 2 * c2], kf[row * 128 + 2 * c2 + 1]);
        }
        const float* wf = (const float*)vu_w2;
        for (int g = t; g < 128 * 64; g += 512) {
            int row = g >> 6, c2 = g & 63;
            sm.v2.w2s[W2ROW(row) + c2] = packbf(wf[row * 128 + 2 * c2], wf[row * 128 + 2 * c2 + 1]);
        }
    }
    for (int g = t; g < SS; g += 512) sm.qrow[g] = qseq[b * SS + g];
    __syncthreads();

    // ---- build fused interleaved columns: rw2ea[k] = ((w2@er)[32q+k][d], (w2@ad)[32q+k][d]) ----
    f32x2 rw2ea[32];
#pragma unroll
    for (int k = 0; k < 32; ++k) { rw2ea[k].x = 0.f; rw2ea[k].y = 0.f; }
    f32x2 eab2; eab2.x = 0.f; eab2.y = 0.f;
#pragma unroll 1
    for (int jc = 0; jc < 4; ++jc) {
        f32x2 ea[32];
#pragma unroll
        for (int i = 0; i < 32; ++i) {
            int j = 32 * jc + i;
            ea[i].x = ldw<BF16>(er_w, (size_t)j * DD + d);
            ea[i].y = ldw<BF16>(ad_w, (size_t)j * DD + d);
            float b2j = ldw<BF16>(vu_b2, j);
            f32x2 bs; bs.x = b2j; bs.y = b2j;
            eab2 = pkfma(bs, ea[i], eab2);
        }
#pragma unroll
        for (int k = 0; k < 32; ++k) {
            const uint4* wp = (const uint4*)&sm.v2.w2s[W2ROW(32 * q + k) + 16 * jc];
            uint4 A = wp[0], B = wp[1], C = wp[2], Dv = wp[3];
            unsigned int W[16] = { A.x, A.y, A.z, A.w, B.x, B.y, B.z, B.w,
                                   C.x, C.y, C.z, C.w, Dv.x, Dv.y, Dv.z, Dv.w };
            f32x2 acc = rw2ea[k];
#pragma unroll
            for (int wd = 0; wd < 16; ++wd) {
                float wlo = bfu_lo(W[wd]), whi = bfu_hi(W[wd]);
                f32x2 s0; s0.x = wlo; s0.y = wlo;
                f32x2 s1; s1.x = whi; s1.y = whi;
                acc = pkfma(s0, ea[2 * wd], acc);
                acc = pkfma(s1, ea[2 * wd + 1], acc);
            }
            rw2ea[k] = acc;
        }
    }
    eab2.x += ldw<BF16>(er_b, d);
    eab2.y += ldw<BF16>(ad_b, d);
    __syncthreads();   // w2s consumed -> v2 region becomes tab

    // ---- w1 columns into registers (pairs for pk_fma) ----
    f32x2 rw1a2[16];
    float rw1b[32];
#pragma unroll
    for (int i = 0; i < 16; ++i) {
        int k0 = 32 * q + 2 * i;
        rw1a2[i].x = ldw<BF16>(vu_w1, (size_t)k0 * DD + d);
        rw1a2[i].y = ldw<BF16>(vu_w1, (size_t)(k0 + 1) * DD + d);
    }
#pragma unroll
    for (int i = 0; i < 32; ++i)
        rw1b[i] = ldw<BF16>(vu_w1, (size_t)(DD + 32 * q + i) * DD + d);
    const float b1r = ldw<BF16>(vu_b1, d);

    // ================= PRECOMPUTE: softmax rows + qe-projections =================
    for (int ii = 0; ii < 13; ++ii) {
        const int nrows = (ii == 12) ? 4 : 8;
        {
            int r = t >> 6, w = t & 63;
            if (r < nrows) {
                int row = sm.qrow[8 * ii + r];
                if (BF16) {
                    sm.u.pre.qe8[r][w] = ((const unsigned int*)emb)[((size_t)row << 6) + w];
                } else {
                    const float* ef = (const float*)emb + (((size_t)row) << 7) + 2 * w;
                    sm.u.pre.qe8[r][w] = packbf(ef[0], ef[1]);
                }
            }
        }
        __syncthreads();

        // logits + softmax: wave wv handles s = 8*ii + wv (lane m = l)
        if (wv < nrows) {
            int m = l;
            int mc = (m < MM) ? m : (MM - 1);
            float a0 = 0.f, a1 = 0.f, a2 = 0.f, a3 = 0.f;
#pragma unroll
            for (int j = 0; j < 32; ++j) {
                uint2 kw = *(const uint2*)&sm.u.pre.key_w[mc * KROW + 2 * j];
                uint2 qw = *(const uint2*)&sm.u.pre.qe8[wv][2 * j];
                a0 = fmaf(bfu_lo(kw.x), bfu_lo(qw.x), a0);
                a1 = fmaf(bfu_hi(kw.x), bfu_hi(qw.x), a1);
                a2 = fmaf(bfu_lo(kw.y), bfu_lo(qw.y), a2);
                a3 = fmaf(bfu_hi(kw.y), bfu_hi(qw.y), a3);
            }
            float lg = (a0 + a1) + (a2 + a3);
            if (m >= MM) lg = -1e30f;
            float mx = lg;
#pragma unroll
            for (int o = 32; o > 0; o >>= 1) mx = fmaxf(mx, __shfl_xor(mx, o));
            float p = (m < MM) ? __expf(lg - mx) : 0.f;
            float sum = p;
#pragma unroll
            for (int o = 32; o > 0; o >>= 1) sum += __shfl_xor(sum, o);
            p = p / sum;                       // zeros for m in [50,64)
            float pn = __shfl_xor(p, 4);       // partner m^4 (bit2 flip)
            if ((m & 4) == 0)
                sm.v2.tab.wrow_p[8 * ii + wv][(m & 3) * 8 + (m >> 3)] = packbf(p, pn);
        }

        // qe-projection: thread (d,q), k in [32q, 32q+32); quad butterfly reduce
        for (int sr = 0; sr < nrows; ++sr) {
            float p0 = 0.f, p1 = 0.f;
#pragma unroll
            for (int i = 0; i < 16; ++i) {
                unsigned int uw = sm.u.pre.qe8[sr][16 * q + i];
                p0 = fmaf(rw1b[2 * i],     bfu_lo(uw), p0);
                p1 = fmaf(rw1b[2 * i + 1], bfu_hi(uw), p1);
            }
            float qpv = qbf_add(p0 + p1);
            if (q == 0) sm.v2.tab.qp_all[8 * ii + sr][d] = f2bf_bits(qpv);
        }
        __syncthreads();
    }

    // save last qe (s=99 lives in qe8[3]); init scan state
    if (t < 64) {
        unsigned int uw = sm.u.pre.qe8[3][t];
        sm.qlast[2 * t]     = bfu_lo(uw);
        sm.qlast[2 * t + 1] = bfu_hi(uw);
    }
    f32x2 v2[7];
#pragma unroll
    for (int p = 0; p < 7; ++p) { v2[p].x = 0.f; v2[p].y = 0.f; }
    f32x2 wr2[7];
    {
        const uint4* wp = (const uint4*)&sm.v2.tab.wrow_p[0][q * 8];
        uint4 w0 = wp[0], w1 = wp[1];
        unsigned int ww[8] = { w0.x, w0.y, w0.z, w0.w, w1.x, w1.y, w1.z, w1.w };
#pragma unroll
        for (int p = 0; p < 7; ++p) { wr2[p].x = bfu_lo(ww[p]); wr2[p].y = bfu_hi(ww[p]); }
    }
    if (t < 152) sm.u.run.xread[t] = 0.f;   // read0 = 0 (v0 = 0)
    __syncthreads();

    // ================= SCAN: 2 barriers per step =================
    for (int s = 0; s < SS; ++s) {
        // ---- E: h = tanh(read @ w1a + qp + b1); write duplicated ----
        {
            float qpv = bf2f(sm.v2.tab.qp_all[s][d]);
            const float4* xp = (const float4*)&sm.u.run.xread[40 * q];
            f32x2 acc2; acc2.x = 0.f; acc2.y = 0.f;
#pragma unroll
            for (int j = 0; j < 8; ++j) {
                float4 X = xp[j];
                f32x2 x01; x01.x = X.x; x01.y = X.y;
                f32x2 x23; x23.x = X.z; x23.y = X.w;
                acc2 = pkfma(rw1a2[2 * j], x01, acc2);
                acc2 = pkfma(rw1a2[2 * j + 1], x23, acc2);
            }
            float acc = qbf_add(acc2.x + acc2.y);
            float hh = fast_tanh(acc + qpv + b1r);
            if (q == 0) {
                f32x2 hd; hd.x = hh; hd.y = hh;
                *(f32x2*)&sm.u.run.xhdup[DUPW(2 * d)] = hd;
            }
        }
        __syncthreads();

        // ---- G: (e,a) via interleaved pk matvec; v-update; next read ----
        {
            f32x2 acc2; acc2.x = 0.f; acc2.y = 0.f;
#pragma unroll
            for (int blk = 0; blk < 2; ++blk) {
                const float4* xp = (const float4*)&sm.u.run.xhdup[80 * q + 40 * blk];
#pragma unroll
                for (int j = 0; j < 8; ++j) {
                    float4 X = xp[j];           // (h_k, h_k, h_{k+1}, h_{k+1})
                    f32x2 s0; s0.x = X.x; s0.y = X.y;
                    f32x2 s1; s1.x = X.z; s1.y = X.w;
                    int k = 16 * blk + 2 * j;
                    acc2 = pkfma(rw2ea[k], s0, acc2);
                    acc2 = pkfma(rw2ea[k + 1], s1, acc2);
                }
            }
            float ae = qbf_add(acc2.x);
            float aa = qbf_add(acc2.y);
            float e = fast_sigmoid(ae + eab2.x);
            float a = fast_tanh(aa + eab2.y);
            f32x2 me; me.x = -e; me.y = -e;
            f32x2 av; av.x = a;  av.y = a;
#pragma unroll
            for (int p = 0; p < 7; ++p)
                v2[p] = pkfma(wr2[p], pkfma(me, v2[p], av), v2[p]);
            if (s + 1 < SS) {   // advance wrow; at s=99 keep wrow[99] for the final read
                const uint4* wp = (const uint4*)&sm.v2.tab.wrow_p[s + 1][q * 8];
                uint4 w0 = wp[0], w1 = wp[1];
                unsigned int ww[8] = { w0.x, w0.y, w0.z, w0.w, w1.x, w1.y, w1.z, w1.w };
#pragma unroll
                for (int p = 0; p < 7; ++p) { wr2[p].x = bfu_lo(ww[p]); wr2[p].y = bfu_hi(ww[p]); }
            }
            f32x2 racc; racc.x = 0.f; racc.y = 0.f;
#pragma unroll
            for (int p = 0; p < 7; ++p)
                racc = pkfma(wr2[p], v2[p], racc);
            float rr = qbf_add(racc.x + racc.y);
            if (q == 0) sm.u.run.xread[XW(d)] = rr;
        }
        __syncthreads();
    }

    // ---- Epilogue: xread holds final read (f32); qlast holds qe[99] ----
    float acc = 0.f;
    {
        const float4* xp = (const float4*)&sm.u.run.xread[40 * q];
        const float4* qp4 = (const float4*)&sm.qlast[32 * q];
#pragma unroll
        for (int j = 0; j < 8; ++j) {
            float4 xv = xp[j];
            float4 qv = qp4[j];
            int k = 32 * q + 4 * j;
            acc = fmaf(ldw<BF16>(out_w1, (size_t)k * DD + d),       xv.x, acc);
            acc = fmaf(ldw<BF16>(out_w1, (size_t)(k + 1) * DD + d), xv.y, acc);
            acc = fmaf(ldw<BF16>(out_w1, (size_t)(k + 2) * DD + d), xv.z, acc);
            acc = fmaf(ldw<BF16>(out_w1, (size_t)(k + 3) * DD + d), xv.w, acc);
            acc = fmaf(ldw<BF16>(out_w1, (size_t)(DD + k) * DD + d),     qv.x, acc);
            acc = fmaf(ldw<BF16>(out_w1, (size_t)(DD + k + 1) * DD + d), qv.y, acc);
            acc = fmaf(ldw<BF16>(out_w1, (size_t)(DD + k + 2) * DD + d), qv.z, acc);
            acc = fmaf(ldw<BF16>(out_w1, (size_t)(DD + k + 3) * DD + d), qv.w, acc);
        }
    }
    acc = qbf_add(acc);
    float h1 = fmaxf(acc + ldw<BF16>(out_b1, d), 0.f);
    if (q == 0) sm.u.run.h1f[d] = h1;
    __syncthreads();

    if (t < 64) {
        float xs = fmaf(sm.u.run.h1f[t], ldw<BF16>(out_w2, t),
                        sm.u.run.h1f[64 + t] * ldw<BF16>(out_w2, 64 + t));
#pragma unroll
        for (int o = 32; o > 0; o >>= 1) xs += __shfl_xor(xs, o);
        if (t == 0) {
            float pred = fast_sigmoid(xs + ldw<BF16>(out_b2, 0));
            if (BF16) ((unsigned short*)outp)[b] = f2bf_bits(pred);
            else      ((float*)outp)[b] = pred;
        }
    }
}

__global__ __launch_bounds__(512) void DKVMN_78546361909953_kernel(
    const int* __restrict__ qseq,
    const void* emb, const void* key,
    const void* vu_w1, const void* vu_b1, const void* vu_w2, const void* vu_b2,
    const void* er_w, const void* er_b, const void* ad_w, const void* ad_b,
    const void* out_w1, const void* out_b1, const void* out_w2, const void* out_b2,
    void* outp)
{
    __shared__ SmemT sm;

    // Runtime storage-dtype detection (proven rounds 5-10: BF16 path taken).
    const unsigned int* eu = (const unsigned int*)emb;
    int cnt = 0;
    for (int i = 0; i < 32; ++i) {
        unsigned int e8 = (eu[i] >> 7) & 0xFFu;
        cnt += (e8 >= 100u && e8 <= 127u) ? 1 : 0;
    }
    if (cnt >= 16)
        dkvmn_impl<true>(qseq, emb, key, vu_w1, vu_b1, vu_w2, vu_b2,
                         er_w, er_b, ad_w, ad_b, out_w1, out_b1, out_w2, out_b2, outp, sm);
    else
        dkvmn_impl<false>(qseq, emb, key, vu_w1, vu_b1, vu_w2, vu_b2,
                          er_w, er_b, ad_w, ad_b, out_w1, out_b1, out_w2, out_b2, outp, sm);
}

extern "C" void kernel_launch(void* const* d_in, const int* in_sizes, int n_in,
                              void* d_out, int out_size, void* d_ws, size_t ws_size,
                              hipStream_t stream) {
    const int* qseq = (const int*)d_in[0];
    // d_in[1] = answer_seq: unused by the reference
    DKVMN_78546361909953_kernel<<<BB, 512, 0, stream>>>(
        qseq,
        d_in[2], d_in[3], d_in[4], d_in[5], d_in[6], d_in[7],
        d_in[8], d_in[9], d_in[10], d_in[11],
        d_in[12], d_in[13], d_in[14], d_in[15],
        d_out);
}